// Round 1
// baseline (396.779 us; speedup 1.0000x reference)
//
#include <hip/hip_runtime.h>
#include <math.h>

#define K 17
#define WAVE 64

__device__ __forceinline__ bool lex_less(float ad, int ai, float bd, int bi) {
    // strict (d2, idx) lexicographic less — matches lax.top_k stable tie-break
    return (ad < bd) || (ad == bd && ai < bi);
}

__global__ __launch_bounds__(WAVE) void knn_kernel(
    const float* __restrict__ pos, const float* __restrict__ box,
    float* __restrict__ out, int N)
{
    const int i    = blockIdx.x;    // query point
    const int lane = threadIdx.x;   // 0..63

    const float bx = box[0], by = box[1], bz = box[2];
    const float hx = 0.5f * bx, hy = 0.5f * by, hz = 0.5f * bz;

    const float xi = pos[3 * i + 0];
    const float yi = pos[3 * i + 1];
    const float zi = pos[3 * i + 2];

    // per-lane sorted top-K (ascending by (d2, idx))
    float d[K];
    int   id[K];
#pragma unroll
    for (int m = 0; m < K; ++m) { d[m] = INFINITY; id[m] = 0x7fffffff; }

    for (int j0 = 0; j0 < N; j0 += WAVE) {
        const int j = j0 + lane;
        float cd = INFINITY;
        int   ci = 0x7fffffff;
        if (j < N && j != i) {
            float dx = __fsub_rn(xi, pos[3 * j + 0]);
            float dy = __fsub_rn(yi, pos[3 * j + 1]);
            float dz = __fsub_rn(zi, pos[3 * j + 2]);
            // minimum-image wrap; exact (Sterbenz) and equivalent to
            // diff - box*rint(diff/box) except at |diff|~box/2 where d2>=625
            // (irrelevant to top-17 at kNN distances ~<7)
            dx = dx > hx ? __fsub_rn(dx, bx) : (dx < -hx ? __fadd_rn(dx, bx) : dx);
            dy = dy > hy ? __fsub_rn(dy, by) : (dy < -hy ? __fadd_rn(dy, by) : dy);
            dz = dz > hz ? __fsub_rn(dz, bz) : (dz < -hz ? __fadd_rn(dz, bz) : dz);
            cd = __fadd_rn(__fadd_rn(__fmul_rn(dx, dx), __fmul_rn(dy, dy)),
                           __fmul_rn(dz, dz));
            ci = j;
        }
        // insert if better than lane-local worst
        if (lex_less(cd, ci, d[K - 1], id[K - 1])) {
            bool lt[K];
#pragma unroll
            for (int m = 0; m < K; ++m) lt[m] = lex_less(cd, ci, d[m], id[m]);
#pragma unroll
            for (int m = K - 1; m >= 1; --m) {
                d[m]  = lt[m - 1] ? d[m - 1]  : (lt[m] ? cd : d[m]);
                id[m] = lt[m - 1] ? id[m - 1] : (lt[m] ? ci : id[m]);
            }
            d[0]  = lt[0] ? cd : d[0];
            id[0] = lt[0] ? ci : id[0];
        }
    }

    // output layout: [src row | neighbor row | dist], all float32
    const long kN = (long)N * K;
    float* out_src = out;
    float* out_nbr = out + kN;
    float* out_dst = out + 2 * kN;

    if (lane < K) out_src[(long)i * K + lane] = (float)i;

    // merge 64 sorted lists: K rounds of wave-wide lexicographic argmin
#pragma unroll 1
    for (int e = 0; e < K; ++e) {
        float bv = d[0];
        int   bi = id[0];
#pragma unroll
        for (int off = 32; off >= 1; off >>= 1) {
            float ov = __shfl_xor(bv, off, WAVE);
            int   oi = __shfl_xor(bi, off, WAVE);
            if (lex_less(ov, oi, bv, bi)) { bv = ov; bi = oi; }
        }
        // pop winner from the (unique) owning lane
        if (d[0] == bv && id[0] == bi) {
#pragma unroll
            for (int m = 0; m < K - 1; ++m) { d[m] = d[m + 1]; id[m] = id[m + 1]; }
            d[K - 1] = INFINITY;
            id[K - 1] = 0x7fffffff;
        }
        if (lane == 0) {
            out_nbr[(long)i * K + e] = (float)bi;
            out_dst[(long)i * K + e] = __fsqrt_rn(bv);
        }
    }
}

extern "C" void kernel_launch(void* const* d_in, const int* in_sizes, int n_in,
                              void* d_out, int out_size, void* d_ws, size_t ws_size,
                              hipStream_t stream) {
    const float* pos = (const float*)d_in[0];
    const float* box = (const float*)d_in[1];
    const int N = in_sizes[0] / 3;
    knn_kernel<<<dim3(N), dim3(WAVE), 0, stream>>>(pos, box, (float*)d_out, N);
}

// Round 2
// 166.252 us; speedup vs baseline: 2.3866x; 2.3866x over previous
//
#include <hip/hip_runtime.h>
#include <math.h>

#define K 17
#define WAVE 64
#define G 10
#define CELLS (G*G*G)

__device__ __forceinline__ bool lex_less(float ad, int ai, float bd, int bi) {
    // strict (d2, idx) lexicographic less — matches lax.top_k stable tie-break
    return (ad < bd) || (ad == bd && ai < bi);
}

// ---------- prep: counting-sort points into cells ----------

__global__ void count_kernel(const float* __restrict__ pos, const float* __restrict__ box,
                             int* __restrict__ bins, int N) {
    int i = blockIdx.x * blockDim.x + threadIdx.x;
    if (i >= N) return;
    float invx = (float)G / box[0], invy = (float)G / box[1], invz = (float)G / box[2];
    int cx = min((int)(pos[3*i+0] * invx), G-1);
    int cy = min((int)(pos[3*i+1] * invy), G-1);
    int cz = min((int)(pos[3*i+2] * invz), G-1);
    atomicAdd(&bins[(cz*G + cy)*G + cx], 1);
}

__global__ __launch_bounds__(1024) void scan_kernel(int* __restrict__ bins,
                                                    int* __restrict__ cursor, int N) {
    __shared__ int s[1024];
    int t = threadIdx.x;
    int v = (t < CELLS) ? bins[t] : 0;
    s[t] = v;
    __syncthreads();
    for (int off = 1; off < 1024; off <<= 1) {
        int u = (t >= off) ? s[t - off] : 0;
        __syncthreads();
        s[t] += u;
        __syncthreads();
    }
    int excl = s[t] - v;                 // exclusive prefix sum
    if (t < CELLS) { bins[t] = excl; cursor[t] = excl; }
    if (t == 0) bins[CELLS] = N;
}

__global__ void scatter_kernel(const float* __restrict__ pos, const float* __restrict__ box,
                               int* __restrict__ cursor, float4* __restrict__ sp4, int N) {
    int i = blockIdx.x * blockDim.x + threadIdx.x;
    if (i >= N) return;
    float x = pos[3*i+0], y = pos[3*i+1], z = pos[3*i+2];
    float invx = (float)G / box[0], invy = (float)G / box[1], invz = (float)G / box[2];
    int cx = min((int)(x * invx), G-1);
    int cy = min((int)(y * invy), G-1);
    int cz = min((int)(z * invz), G-1);
    int cell = (cz*G + cy)*G + cx;
    int slot = atomicAdd(&cursor[cell], 1);
    sp4[slot] = make_float4(x, y, z, __int_as_float(i));
}

// ---------- main: one wave per query, ring-expanding cell search ----------

__global__ __launch_bounds__(WAVE) void knn_cell_kernel(
    const float* __restrict__ pos, const float* __restrict__ box,
    const float4* __restrict__ sp4, const int* __restrict__ cellStart,
    float* __restrict__ out, int N)
{
    const int i = blockIdx.x;
    const int lane = threadIdx.x;

    const float bx = box[0], by = box[1], bz = box[2];
    const float hx = 0.5f*bx, hy = 0.5f*by, hz = 0.5f*bz;
    const float invx = (float)G/bx, invy = (float)G/by, invz = (float)G/bz;
    const float cmin = fminf(bx, fminf(by, bz)) / (float)G;  // min cell width

    const float xi = pos[3*i+0], yi = pos[3*i+1], zi = pos[3*i+2];
    const int cx = min((int)(xi*invx), G-1);
    const int cy = min((int)(yi*invy), G-1);
    const int cz = min((int)(zi*invz), G-1);

    // per-lane sorted top-K (ascending by (d2, idx))
    float d[K]; int id[K];
#pragma unroll
    for (int m = 0; m < K; ++m) { d[m] = INFINITY; id[m] = 0x7fffffff; }

    float md = INFINITY; int mi = 0x7fffffff;   // lane e<K holds e-th best after merge
    bool done = false;

#pragma unroll 1
    for (int r = 1; r <= G/2 && !done; ++r) {
        const int lo = -r;
        const int hi = (2*r+1 > G) ? (G-1-r) : r;   // dedup when ring wraps whole box
#pragma unroll 1
        for (int oz = lo; oz <= hi; ++oz) {
            int uz = cz + oz; uz += (uz < 0) ? G : 0; uz -= (uz >= G) ? G : 0;
#pragma unroll 1
            for (int oy = lo; oy <= hi; ++oy) {
                int uy = cy + oy; uy += (uy < 0) ? G : 0; uy -= (uy >= G) ? G : 0;
                const int rowbase = (uz*G + uy)*G;
                const bool rowFull = (r == 1) || (max(abs(oy), abs(oz)) >= r);

                // x-cells of this row as 1-2 contiguous wrapped ranges [u0a,u1a],[u0b,u1b]
                int u0a, u1a, u0b = 0, u1b = -1;
                if (rowFull) {
                    int a = cx + lo, b = cx + hi;
                    if (a < 0)       { u0a = a + G; u1a = G - 1; u0b = 0; u1b = b; }
                    else if (b >= G) { u0a = a;     u1a = G - 1; u0b = 0; u1b = b - G; }
                    else             { u0a = a;     u1a = b; }
                } else {
                    int ux1 = cx - r; ux1 += (ux1 < 0) ? G : 0;
                    u0a = u1a = ux1;
                    if (hi >= r) { int ux2 = cx + r; ux2 -= (ux2 >= G) ? G : 0; u0b = u1b = ux2; }
                }

                int rs1 = cellStart[rowbase + u0a];
                int l1  = cellStart[rowbase + u1a + 1] - rs1;
                int rs2 = 0, l2 = 0;
                if (u1b >= u0b) {
                    rs2 = cellStart[rowbase + u0b];
                    l2  = cellStart[rowbase + u1b + 1] - rs2;
                }
                const int cnt = l1 + l2;

#pragma unroll 1
                for (int t0 = 0; t0 < cnt; t0 += WAVE) {
                    const int t = t0 + lane;
                    float cd = INFINITY; int ci = 0x7fffffff;
                    if (t < cnt) {
                        int slot = (t < l1) ? (rs1 + t) : (rs2 + t - l1);
                        float4 p = sp4[slot];
                        int j = __float_as_int(p.w);
                        if (j != i) {
                            float dx = __fsub_rn(xi, p.x);
                            float dy = __fsub_rn(yi, p.y);
                            float dz = __fsub_rn(zi, p.z);
                            dx = dx > hx ? __fsub_rn(dx, bx) : (dx < -hx ? __fadd_rn(dx, bx) : dx);
                            dy = dy > hy ? __fsub_rn(dy, by) : (dy < -hy ? __fadd_rn(dy, by) : dy);
                            dz = dz > hz ? __fsub_rn(dz, bz) : (dz < -hz ? __fadd_rn(dz, bz) : dz);
                            cd = __fadd_rn(__fadd_rn(__fmul_rn(dx, dx), __fmul_rn(dy, dy)),
                                           __fmul_rn(dz, dz));
                            ci = j;
                        }
                    }
                    if (lex_less(cd, ci, d[K-1], id[K-1])) {
                        bool lt[K];
#pragma unroll
                        for (int m = 0; m < K; ++m) lt[m] = lex_less(cd, ci, d[m], id[m]);
#pragma unroll
                        for (int m = K - 1; m >= 1; --m) {
                            d[m]  = lt[m-1] ? d[m-1]  : (lt[m] ? cd : d[m]);
                            id[m] = lt[m-1] ? id[m-1] : (lt[m] ? ci : id[m]);
                        }
                        d[0]  = lt[0] ? cd : d[0];
                        id[0] = lt[0] ? ci : id[0];
                    }
                }
            }
        }

        // merge 64 per-lane sorted lists: K rounds of wave-wide lex argmin.
        // Winner of round e is kept on lane e (md/mi). Lists are consumed.
#pragma unroll 1
        for (int e = 0; e < K; ++e) {
            float bv = d[0]; int bi = id[0];
#pragma unroll
            for (int off = 32; off >= 1; off >>= 1) {
                float ov = __shfl_xor(bv, off, WAVE);
                int   oi = __shfl_xor(bi, off, WAVE);
                if (lex_less(ov, oi, bv, bi)) { bv = ov; bi = oi; }
            }
            if (d[0] == bv && id[0] == bi) {   // unique owner (finite); all-INF case harmless
#pragma unroll
                for (int m = 0; m < K - 1; ++m) { d[m] = d[m+1]; id[m] = id[m+1]; }
                d[K-1] = INFINITY; id[K-1] = 0x7fffffff;
            }
            if (lane == e) { md = bv; mi = bi; }
        }

        // stop if kth distance is inside the guaranteed-covered radius r*cmin
        float d17 = __shfl(md, K - 1);
        done = (r >= G/2) || (d17 < (r*cmin)*(r*cmin)*0.9998f);

        if (!done) {
            // reseed: lanes 0..K-1 carry the current top-K as 1-element lists
#pragma unroll
            for (int m = 0; m < K; ++m) { d[m] = INFINITY; id[m] = 0x7fffffff; }
            if (lane < K) { d[0] = md; id[0] = mi; }
        }
    }

    // output layout: [src row | neighbor row | dist], all float32
    const long kN = (long)N * K;
    if (lane < K) {
        out[(long)i*K + lane]          = (float)i;
        out[kN + (long)i*K + lane]     = (float)mi;
        out[2*kN + (long)i*K + lane]   = __fsqrt_rn(md);
    }
}

extern "C" void kernel_launch(void* const* d_in, const int* in_sizes, int n_in,
                              void* d_out, int out_size, void* d_ws, size_t ws_size,
                              hipStream_t stream) {
    const float* pos = (const float*)d_in[0];
    const float* box = (const float*)d_in[1];
    const int N = in_sizes[0] / 3;

    // workspace layout (need ~137 KB)
    unsigned char* ws = (unsigned char*)d_ws;
    int*    bins   = (int*)ws;                    // (CELLS+1) ints: counts -> cellStart
    int*    cursor = (int*)(ws + 4352);           // CELLS ints: scatter cursors
    float4* sp4    = (float4*)(ws + 8704);        // N float4: cell-sorted (x,y,z,idx)

    hipMemsetAsync(bins, 0, (CELLS + 1) * sizeof(int), stream);
    count_kernel<<<dim3((N + 255) / 256), dim3(256), 0, stream>>>(pos, box, bins, N);
    scan_kernel<<<dim3(1), dim3(1024), 0, stream>>>(bins, cursor, N);
    scatter_kernel<<<dim3((N + 255) / 256), dim3(256), 0, stream>>>(pos, box, cursor, sp4, N);
    knn_cell_kernel<<<dim3(N), dim3(WAVE), 0, stream>>>(pos, box, sp4, bins, (float*)d_out, N);
}

// Round 4
// 148.671 us; speedup vs baseline: 2.6688x; 1.1183x over previous
//
#include <hip/hip_runtime.h>
#include <math.h>

#define K 17
#define WAVE 64
#define G 10
#define CELLS (G*G*G)
#define L 6          // per-lane list depth in stage 1; safe: cnt<=384 -> <=6 cands/lane

__device__ __forceinline__ bool lex_less(float ad, int ai, float bd, int bi) {
    // strict (d2, idx) lexicographic less — matches lax.top_k stable tie-break
    return (ad < bd) || (ad == bd && ai < bi);
}

// ---------- prep: single-block counting-sort into cells (count+scan+scatter) ----------

__global__ __launch_bounds__(1024) void prep_kernel(
    const float* __restrict__ pos, const float* __restrict__ box,
    int* __restrict__ cellStart /* CELLS+1 */, float4* __restrict__ sp4, int N)
{
    __shared__ int s[1024];       // counts then inclusive scan
    __shared__ int cur[CELLS];    // scatter cursors
    const int t = threadIdx.x;
    s[t] = 0;
    __syncthreads();

    const float invx = (float)G / box[0];
    const float invy = (float)G / box[1];
    const float invz = (float)G / box[2];

    for (int p = t; p < N; p += 1024) {
        int cx = min((int)(pos[3*p+0] * invx), G-1);
        int cy = min((int)(pos[3*p+1] * invy), G-1);
        int cz = min((int)(pos[3*p+2] * invz), G-1);
        atomicAdd(&s[(cz*G + cy)*G + cx], 1);
    }
    __syncthreads();
    int v = s[t];
    for (int off = 1; off < 1024; off <<= 1) {
        int u = (t >= off) ? s[t - off] : 0;
        __syncthreads();
        s[t] += u;
        __syncthreads();
    }
    int excl = s[t] - v;
    if (t < CELLS) { cellStart[t] = excl; cur[t] = excl; }
    if (t == 0) cellStart[CELLS] = N;
    __syncthreads();

    for (int p = t; p < N; p += 1024) {
        float x = pos[3*p+0], y = pos[3*p+1], z = pos[3*p+2];
        int cx = min((int)(x * invx), G-1);
        int cy = min((int)(y * invy), G-1);
        int cz = min((int)(z * invz), G-1);
        int slot = atomicAdd(&cur[(cz*G + cy)*G + cx], 1);
        sp4[slot] = make_float4(x, y, z, __int_as_float(p));
    }
}

// ---------- main: one wave per query; flattened 27-cell scan + rare ring fallback ----------
// LESSON (round 3): __shfl == ds_bpermute reads 0 from EXEC-inactive source lanes.
// Every shuffle below executes under wave-UNIFORM control flow (uniform trip counts,
// clamped indices) — never inside a divergently-exited loop.

__global__ __launch_bounds__(256) void knn_main(
    const float* __restrict__ pos, const float* __restrict__ box,
    const float4* __restrict__ sp4, const int* __restrict__ cellStart,
    float* __restrict__ out, int N)
{
    const int lane = threadIdx.x & 63;
    const int i = blockIdx.x * 4 + (threadIdx.x >> 6);
    if (i >= N) return;   // wave-uniform (N % 4 == 0 for N=8192; guard for generality)

    const float bx = box[0], by = box[1], bz = box[2];
    const float hx = 0.5f*bx, hy = 0.5f*by, hz = 0.5f*bz;
    const float invx = (float)G/bx, invy = (float)G/by, invz = (float)G/bz;
    const float cmin = fminf(bx, fminf(by, bz)) / (float)G;

    const float xi = pos[3*i+0], yi = pos[3*i+1], zi = pos[3*i+2];
    const int cx = min((int)(xi*invx), G-1);
    const int cy = min((int)(yi*invy), G-1);
    const int cz = min((int)(zi*invz), G-1);

    // ---- stage 1: 27-cell neighborhood as <=18 wrapped x-segments, lane-parallel setup
    int segStart = 0, segLen = 0;
    if (lane < 18) {
        int r9 = lane >> 1, part = lane & 1;
        int oz = r9 / 3 - 1, oy = r9 % 3 - 1;
        int uz = cz + oz; uz += (uz < 0) ? G : 0; uz -= (uz >= G) ? G : 0;
        int uy = cy + oy; uy += (uy < 0) ? G : 0; uy -= (uy >= G) ? G : 0;
        int rowbase = (uz*G + uy)*G;
        int u0 = 0, u1 = -1;
        if (cx == 0)        { if (part == 0) { u0 = G-1; u1 = G-1; } else { u0 = 0; u1 = 1; } }
        else if (cx == G-1) { if (part == 0) { u0 = G-2; u1 = G-1; } else { u0 = 0; u1 = 0; } }
        else if (part == 0) { u0 = cx-1; u1 = cx+1; }
        if (u1 >= u0) {
            segStart = cellStart[rowbase + u0];
            segLen   = cellStart[rowbase + u1 + 1] - segStart;
        }
    }
    // wave-inclusive prefix sum of segLen (full wave active)
    int incl = segLen;
#pragma unroll
    for (int off = 1; off < 64; off <<= 1) {
        int u = __shfl_up(incl, off, WAVE);
        if (lane >= off) incl += u;
    }
    const int ecum = incl - segLen;          // lanes >=18: ecum == cnt (pads search)
    const int cnt  = __shfl(incl, 63, WAVE);
    const bool overflow = (cnt > WAVE * L);  // never for uniform data; exact-safety net

    float sd[L]; int sid[L];
#pragma unroll
    for (int m = 0; m < L; ++m) { sd[m] = INFINITY; sid[m] = 0x7fffffff; }

    if (!overflow) {
        // UNIFORM trip count: all lanes iterate together; t>=cnt lanes clamp the
        // search index so every __shfl runs with full EXEC.
#pragma unroll 1
        for (int t0 = 0; t0 < cnt; t0 += WAVE) {
            const int t  = t0 + lane;
            const int tc = (t < cnt) ? t : (cnt - 1);
            // largest s with ecum[s] <= tc, via shuffle binary search
            int lo = 0;
#pragma unroll
            for (int st = 32; st >= 1; st >>= 1) {
                int pe = __shfl(ecum, lo + st, WAVE);
                lo = (pe <= tc) ? lo + st : lo;
            }
            int ss = __shfl(segStart, lo, WAVE);
            int se = __shfl(ecum, lo, WAVE);
            float4 p = sp4[ss + (tc - se)];
            int j = __float_as_int(p.w);
            float cd = INFINITY; int ci = 0x7fffffff;
            if (t < cnt && j != i) {
                float dx = __fsub_rn(xi, p.x);
                float dy = __fsub_rn(yi, p.y);
                float dz = __fsub_rn(zi, p.z);
                dx = dx > hx ? __fsub_rn(dx, bx) : (dx < -hx ? __fadd_rn(dx, bx) : dx);
                dy = dy > hy ? __fsub_rn(dy, by) : (dy < -hy ? __fadd_rn(dy, by) : dy);
                dz = dz > hz ? __fsub_rn(dz, bz) : (dz < -hz ? __fadd_rn(dz, bz) : dz);
                cd = __fadd_rn(__fadd_rn(__fmul_rn(dx, dx), __fmul_rn(dy, dy)),
                               __fmul_rn(dz, dz));
                ci = j;
            }
            if (lex_less(cd, ci, sd[L-1], sid[L-1])) {
                bool lt[L];
#pragma unroll
                for (int m = 0; m < L; ++m) lt[m] = lex_less(cd, ci, sd[m], sid[m]);
#pragma unroll
                for (int m = L-1; m >= 1; --m) {
                    sd[m]  = lt[m-1] ? sd[m-1]  : (lt[m] ? cd : sd[m]);
                    sid[m] = lt[m-1] ? sid[m-1] : (lt[m] ? ci : sid[m]);
                }
                sd[0]  = lt[0] ? cd : sd[0];
                sid[0] = lt[0] ? ci : sid[0];
            }
        }
    }

    float md = INFINITY; int mi = 0x7fffffff;   // lane e<K holds e-th best after merge
    // ---- stage-1 merge: K rounds of wave lex-argmin over per-lane sorted L-lists
#pragma unroll 1
    for (int e = 0; e < K; ++e) {
        float bv = sd[0]; int bi = sid[0];
#pragma unroll
        for (int off = 32; off >= 1; off >>= 1) {
            float ov = __shfl_xor(bv, off, WAVE);
            int   oi = __shfl_xor(bi, off, WAVE);
            if (lex_less(ov, oi, bv, bi)) { bv = ov; bi = oi; }
        }
        if (sd[0] == bv && sid[0] == bi) {
#pragma unroll
            for (int m = 0; m < L-1; ++m) { sd[m] = sd[m+1]; sid[m] = sid[m+1]; }
            sd[L-1] = INFINITY; sid[L-1] = 0x7fffffff;
        }
        if (lane == e) { md = bv; mi = bi; }
    }

    float d17 = __shfl(md, K - 1, WAVE);
    bool done = !overflow && (d17 < cmin*cmin*0.9998f);

    if (!done) {
        // ---- rare fallback: ring expansion with full-K lists (proven round-2 path)
        float d[K]; int id[K];
#pragma unroll
        for (int m = 0; m < K; ++m) { d[m] = INFINITY; id[m] = 0x7fffffff; }
        int rstart;
        if (overflow) rstart = 1;                     // full rescan from scratch
        else { rstart = 2; if (lane < K) { d[0] = md; id[0] = mi; } }

#pragma unroll 1
        for (int r = rstart; r <= G/2 && !done; ++r) {
            const int lo = -r;
            const int hi = (2*r+1 > G) ? (G-1-r) : r;
#pragma unroll 1
            for (int oz = lo; oz <= hi; ++oz) {
                int uz = cz + oz; uz += (uz < 0) ? G : 0; uz -= (uz >= G) ? G : 0;
#pragma unroll 1
                for (int oy = lo; oy <= hi; ++oy) {
                    int uy = cy + oy; uy += (uy < 0) ? G : 0; uy -= (uy >= G) ? G : 0;
                    const int rowbase = (uz*G + uy)*G;
                    const bool rowFull = (r == 1) || (max(abs(oy), abs(oz)) >= r);

                    int u0a, u1a, u0b = 0, u1b = -1;
                    if (rowFull) {
                        int a = cx + lo, b = cx + hi;
                        if (a < 0)       { u0a = a + G; u1a = G - 1; u0b = 0; u1b = b; }
                        else if (b >= G) { u0a = a;     u1a = G - 1; u0b = 0; u1b = b - G; }
                        else             { u0a = a;     u1a = b; }
                    } else {
                        int ux1 = cx - r; ux1 += (ux1 < 0) ? G : 0;
                        u0a = u1a = ux1;
                        if (hi >= r) { int ux2 = cx + r; ux2 -= (ux2 >= G) ? G : 0; u0b = u1b = ux2; }
                    }

                    int rs1 = cellStart[rowbase + u0a];
                    int l1  = cellStart[rowbase + u1a + 1] - rs1;
                    int rs2 = 0, l2 = 0;
                    if (u1b >= u0b) {
                        rs2 = cellStart[rowbase + u0b];
                        l2  = cellStart[rowbase + u1b + 1] - rs2;
                    }
                    const int cnt2 = l1 + l2;

#pragma unroll 1
                    for (int t0 = 0; t0 < cnt2; t0 += WAVE) {
                        const int t = t0 + lane;
                        float cd = INFINITY; int ci = 0x7fffffff;
                        if (t < cnt2) {
                            int slot = (t < l1) ? (rs1 + t) : (rs2 + t - l1);
                            float4 p = sp4[slot];
                            int j = __float_as_int(p.w);
                            if (j != i) {
                                float dx = __fsub_rn(xi, p.x);
                                float dy = __fsub_rn(yi, p.y);
                                float dz = __fsub_rn(zi, p.z);
                                dx = dx > hx ? __fsub_rn(dx, bx) : (dx < -hx ? __fadd_rn(dx, bx) : dx);
                                dy = dy > hy ? __fsub_rn(dy, by) : (dy < -hy ? __fadd_rn(dy, by) : dy);
                                dz = dz > hz ? __fsub_rn(dz, bz) : (dz < -hz ? __fadd_rn(dz, bz) : dz);
                                cd = __fadd_rn(__fadd_rn(__fmul_rn(dx, dx), __fmul_rn(dy, dy)),
                                               __fmul_rn(dz, dz));
                                ci = j;
                            }
                        }
                        if (lex_less(cd, ci, d[K-1], id[K-1])) {
                            bool lt[K];
#pragma unroll
                            for (int m = 0; m < K; ++m) lt[m] = lex_less(cd, ci, d[m], id[m]);
#pragma unroll
                            for (int m = K-1; m >= 1; --m) {
                                d[m]  = lt[m-1] ? d[m-1]  : (lt[m] ? cd : d[m]);
                                id[m] = lt[m-1] ? id[m-1] : (lt[m] ? ci : id[m]);
                            }
                            d[0]  = lt[0] ? cd : d[0];
                            id[0] = lt[0] ? ci : id[0];
                        }
                    }
                }
            }

#pragma unroll 1
            for (int e = 0; e < K; ++e) {
                float bv = d[0]; int bi = id[0];
#pragma unroll
                for (int off = 32; off >= 1; off >>= 1) {
                    float ov = __shfl_xor(bv, off, WAVE);
                    int   oi = __shfl_xor(bi, off, WAVE);
                    if (lex_less(ov, oi, bv, bi)) { bv = ov; bi = oi; }
                }
                if (d[0] == bv && id[0] == bi) {
#pragma unroll
                    for (int m = 0; m < K-1; ++m) { d[m] = d[m+1]; id[m] = id[m+1]; }
                    d[K-1] = INFINITY; id[K-1] = 0x7fffffff;
                }
                if (lane == e) { md = bv; mi = bi; }
            }

            d17 = __shfl(md, K - 1, WAVE);
            done = (r >= G/2) || (d17 < (r*cmin)*(r*cmin)*0.9998f);

            if (!done) {
#pragma unroll
                for (int m = 0; m < K; ++m) { d[m] = INFINITY; id[m] = 0x7fffffff; }
                if (lane < K) { d[0] = md; id[0] = mi; }
            }
        }
    }

    // output layout: [src row | neighbor row | dist], all float32
    const long kN = (long)N * K;
    if (lane < K) {
        out[(long)i*K + lane]        = (float)i;
        out[kN + (long)i*K + lane]   = (float)mi;
        out[2*kN + (long)i*K + lane] = __fsqrt_rn(md);
    }
}

extern "C" void kernel_launch(void* const* d_in, const int* in_sizes, int n_in,
                              void* d_out, int out_size, void* d_ws, size_t ws_size,
                              hipStream_t stream) {
    const float* pos = (const float*)d_in[0];
    const float* box = (const float*)d_in[1];
    const int N = in_sizes[0] / 3;

    unsigned char* ws = (unsigned char*)d_ws;
    int*    cellStart = (int*)ws;                 // (CELLS+1) ints
    float4* sp4       = (float4*)(ws + 4096);     // N float4: cell-sorted (x,y,z,idx)

    prep_kernel<<<dim3(1), dim3(1024), 0, stream>>>(pos, box, cellStart, sp4, N);
    knn_main<<<dim3((N + 3) / 4), dim3(256), 0, stream>>>(pos, box, sp4, cellStart,
                                                          (float*)d_out, N);
}

// Round 5
// 145.509 us; speedup vs baseline: 2.7268x; 1.0217x over previous
//
#include <hip/hip_runtime.h>
#include <math.h>

#define K 17
#define WAVE 64
#define G 10
#define CELLS (G*G*G)
#define NSLOT 6                     // max candidates per lane (cnt <= 384)
#define KEY_MAX 0xFFFFFFFFFFFFFFFFULL

__device__ __forceinline__ bool lex_less(float ad, int ai, float bd, int bi) {
    return (ad < bd) || (ad == bd && ai < bi);
}

// ---------- prep: single-block counting-sort into cells (unchanged, proven r4) ----------

__global__ __launch_bounds__(1024) void prep_kernel(
    const float* __restrict__ pos, const float* __restrict__ box,
    int* __restrict__ cellStart /* CELLS+1 */, float4* __restrict__ sp4, int N)
{
    __shared__ int s[1024];
    __shared__ int cur[CELLS];
    const int t = threadIdx.x;
    s[t] = 0;
    __syncthreads();

    const float invx = (float)G / box[0];
    const float invy = (float)G / box[1];
    const float invz = (float)G / box[2];

    for (int p = t; p < N; p += 1024) {
        int cx = min((int)(pos[3*p+0] * invx), G-1);
        int cy = min((int)(pos[3*p+1] * invy), G-1);
        int cz = min((int)(pos[3*p+2] * invz), G-1);
        atomicAdd(&s[(cz*G + cy)*G + cx], 1);
    }
    __syncthreads();
    int v = s[t];
    for (int off = 1; off < 1024; off <<= 1) {
        int u = (t >= off) ? s[t - off] : 0;
        __syncthreads();
        s[t] += u;
        __syncthreads();
    }
    int excl = s[t] - v;
    if (t < CELLS) { cellStart[t] = excl; cur[t] = excl; }
    if (t == 0) cellStart[CELLS] = N;
    __syncthreads();

    for (int p = t; p < N; p += 1024) {
        float x = pos[3*p+0], y = pos[3*p+1], z = pos[3*p+2];
        int cx = min((int)(x * invx), G-1);
        int cy = min((int)(y * invy), G-1);
        int cz = min((int)(z * invz), G-1);
        int slot = atomicAdd(&cur[(cz*G + cy)*G + cx], 1);
        sp4[slot] = make_float4(x, y, z, __int_as_float(p));
    }
}

// ---------- main: one wave/query; flattened 27-cell scan + ballot radix-select ----------
// LESSON (r4 counters): dependent ds_bpermute chains (~120cyc each) dominated; this
// version selects top-K via ballot bisection on packed u64 keys (no shuffle chains).
// All shuffles/ballots execute under wave-uniform control flow (r3 lesson).

__global__ __launch_bounds__(256) void knn_main(
    const float* __restrict__ pos, const float* __restrict__ box,
    const float4* __restrict__ sp4, const int* __restrict__ cellStart,
    float* __restrict__ out, int N)
{
    const int lane = threadIdx.x & 63;
    const int wid  = threadIdx.x >> 6;
    const int i = blockIdx.x * 4 + wid;
    if (i >= N) return;

    __shared__ unsigned long long surv[4][24];   // per-wave survivor buffer (17 used)

    const float bx = box[0], by = box[1], bz = box[2];
    const float hx = 0.5f*bx, hy = 0.5f*by, hz = 0.5f*bz;
    const float invx = (float)G/bx, invy = (float)G/by, invz = (float)G/bz;
    const float cmin = fminf(bx, fminf(by, bz)) / (float)G;

    const float xi = pos[3*i+0], yi = pos[3*i+1], zi = pos[3*i+2];
    const int cx = min((int)(xi*invx), G-1);
    const int cy = min((int)(yi*invy), G-1);
    const int cz = min((int)(zi*invz), G-1);

    // ---- stage 1: 27-cell neighborhood as <=18 wrapped x-segments
    int segStart = 0, segLen = 0;
    if (lane < 18) {
        int r9 = lane >> 1, part = lane & 1;
        int oz = r9 / 3 - 1, oy = r9 % 3 - 1;
        int uz = cz + oz; uz += (uz < 0) ? G : 0; uz -= (uz >= G) ? G : 0;
        int uy = cy + oy; uy += (uy < 0) ? G : 0; uy -= (uy >= G) ? G : 0;
        int rowbase = (uz*G + uy)*G;
        int u0 = 0, u1 = -1;
        if (cx == 0)        { if (part == 0) { u0 = G-1; u1 = G-1; } else { u0 = 0; u1 = 1; } }
        else if (cx == G-1) { if (part == 0) { u0 = G-2; u1 = G-1; } else { u0 = 0; u1 = 0; } }
        else if (part == 0) { u0 = cx-1; u1 = cx+1; }
        if (u1 >= u0) {
            segStart = cellStart[rowbase + u0];
            segLen   = cellStart[rowbase + u1 + 1] - segStart;
        }
    }
    // 5-step prefix (values live in lanes<18<32) + explicit sentinel for lanes>=18
    int incl = segLen;
#pragma unroll
    for (int off = 1; off < 32; off <<= 1) {
        int u = __shfl_up(incl, off, WAVE);
        if (lane >= off) incl += u;
    }
    const int cnt = __shfl(incl, 17, WAVE);
    const int ecum = (lane < 18) ? (incl - segLen) : cnt;   // monotone over all 64 lanes

    const bool overflow = (cnt > WAVE * NSLOT);

    unsigned long long key[NSLOT];
#pragma unroll
    for (int m = 0; m < NSLOT; ++m) key[m] = KEY_MAX;

    if (!overflow) {      // wave-uniform branch
        // fully unrolled: 6 independent binary searches + 6 loads interleave (ILP)
#pragma unroll
        for (int m = 0; m < NSLOT; ++m) {
            const int t  = m * WAVE + lane;
            const int tc = (t < cnt) ? t : 0;    // clamp; cnt >= 1 always (own point)
            int lo = 0;
#pragma unroll
            for (int st = 32; st >= 1; st >>= 1) {
                int pe = __shfl(ecum, lo + st, WAVE);
                lo = (pe <= tc) ? lo + st : lo;
            }
            int ss = __shfl(segStart, lo, WAVE);
            int se = __shfl(ecum, lo, WAVE);
            float4 p = sp4[ss + (tc - se)];
            int j = __float_as_int(p.w);
            if (t < cnt && j != i) {
                float dx = __fsub_rn(xi, p.x);
                float dy = __fsub_rn(yi, p.y);
                float dz = __fsub_rn(zi, p.z);
                dx = dx > hx ? __fsub_rn(dx, bx) : (dx < -hx ? __fadd_rn(dx, bx) : dx);
                dy = dy > hy ? __fsub_rn(dy, by) : (dy < -hy ? __fadd_rn(dy, by) : dy);
                dz = dz > hz ? __fsub_rn(dz, bz) : (dz < -hz ? __fadd_rn(dz, bz) : dz);
                float cd = __fadd_rn(__fadd_rn(__fmul_rn(dx, dx), __fmul_rn(dy, dy)),
                                     __fmul_rn(dz, dz));
                // unique 45-bit key: (d2 bits, idx) — u64 order == (d2, idx) lex order
                key[m] = ((unsigned long long)__float_as_uint(cd) << 13) | (unsigned)j;
            }
        }
    }

    // ---- exact top-K threshold via ballot bisection (no cross-lane latency chains)
    const float thr = cmin * cmin * 0.999f;      // < coverage guarantee cmin^2
    unsigned long long lo64 = 0;
    unsigned long long hi64 = ((unsigned long long)__float_as_uint(thr) << 13) | 0x1FFFULL;

    int chi = 0;
#pragma unroll
    for (int m = 0; m < NSLOT; ++m) chi += __popcll(__ballot(key[m] <= hi64));
    const bool ok = !overflow && (chi >= K);     // wave-uniform

    if (ok) {
#pragma unroll 1
        for (int r = 0; r < 45; ++r) {           // range < 2^44 -> converged
            unsigned long long mid = (lo64 + hi64) >> 1;
            int c = 0;
#pragma unroll
            for (int m = 0; m < NSLOT; ++m) c += __popcll(__ballot(key[m] <= mid));
            if (c >= K) hi64 = mid; else lo64 = mid + 1;
        }
        const unsigned long long T = hi64;       // exact 17th-smallest key (unique keys)

        // compact the exactly-17 survivors into per-wave LDS via ballot-prefix
        int base = 0;
#pragma unroll
        for (int m = 0; m < NSLOT; ++m) {
            bool sv = (key[m] <= T);
            unsigned long long mk = __ballot(sv);
            if (sv) {
                int below = __popcll(mk & ((1ULL << lane) - 1ULL));
                surv[wid][base + below] = key[m];
            }
            base += __popcll(mk);
        }
        __asm__ __volatile__("s_waitcnt lgkmcnt(0)" ::: "memory");  // wave-internal LDS sync

        const long kN = (long)N * K;
        if (lane < K) {
            unsigned long long mykey = surv[wid][lane];
            int rank = 0;
#pragma unroll
            for (int m = 0; m < K; ++m)
                rank += (surv[wid][m] < mykey) ? 1 : 0;   // unique keys -> rank 0..16
            float dd = __uint_as_float((unsigned)(mykey >> 13));
            int   nj = (int)(mykey & 0x1FFFULL);
            out[(long)i*K + lane]       = (float)i;
            out[kN + (long)i*K + rank]  = (float)nj;
            out[2*kN + (long)i*K + rank] = __fsqrt_rn(dd);
        }
        return;
    }

    // ---- rare fallback: ring expansion from scratch (proven r2/r4 path, no seeding)
    {
        float d[K]; int id[K];
#pragma unroll
        for (int m = 0; m < K; ++m) { d[m] = INFINITY; id[m] = 0x7fffffff; }
        float md = INFINITY; int mi = 0x7fffffff;
        bool done = false;

#pragma unroll 1
        for (int r = 1; r <= G/2 && !done; ++r) {
            const int lo = -r;
            const int hi = (2*r+1 > G) ? (G-1-r) : r;
#pragma unroll 1
            for (int oz = lo; oz <= hi; ++oz) {
                int uz = cz + oz; uz += (uz < 0) ? G : 0; uz -= (uz >= G) ? G : 0;
#pragma unroll 1
                for (int oy = lo; oy <= hi; ++oy) {
                    int uy = cy + oy; uy += (uy < 0) ? G : 0; uy -= (uy >= G) ? G : 0;
                    const int rowbase = (uz*G + uy)*G;
                    const bool rowFull = (r == 1) || (max(abs(oy), abs(oz)) >= r);

                    int u0a, u1a, u0b = 0, u1b = -1;
                    if (rowFull) {
                        int a = cx + lo, b = cx + hi;
                        if (a < 0)       { u0a = a + G; u1a = G - 1; u0b = 0; u1b = b; }
                        else if (b >= G) { u0a = a;     u1a = G - 1; u0b = 0; u1b = b - G; }
                        else             { u0a = a;     u1a = b; }
                    } else {
                        int ux1 = cx - r; ux1 += (ux1 < 0) ? G : 0;
                        u0a = u1a = ux1;
                        if (hi >= r) { int ux2 = cx + r; ux2 -= (ux2 >= G) ? G : 0; u0b = u1b = ux2; }
                    }

                    int rs1 = cellStart[rowbase + u0a];
                    int l1  = cellStart[rowbase + u1a + 1] - rs1;
                    int rs2 = 0, l2 = 0;
                    if (u1b >= u0b) {
                        rs2 = cellStart[rowbase + u0b];
                        l2  = cellStart[rowbase + u1b + 1] - rs2;
                    }
                    const int cnt2 = l1 + l2;

#pragma unroll 1
                    for (int t0 = 0; t0 < cnt2; t0 += WAVE) {
                        const int t = t0 + lane;
                        float cd = INFINITY; int ci = 0x7fffffff;
                        if (t < cnt2) {
                            int slot = (t < l1) ? (rs1 + t) : (rs2 + t - l1);
                            float4 p = sp4[slot];
                            int j = __float_as_int(p.w);
                            if (j != i) {
                                float dx = __fsub_rn(xi, p.x);
                                float dy = __fsub_rn(yi, p.y);
                                float dz = __fsub_rn(zi, p.z);
                                dx = dx > hx ? __fsub_rn(dx, bx) : (dx < -hx ? __fadd_rn(dx, bx) : dx);
                                dy = dy > hy ? __fsub_rn(dy, by) : (dy < -hy ? __fadd_rn(dy, by) : dy);
                                dz = dz > hz ? __fsub_rn(dz, bz) : (dz < -hz ? __fadd_rn(dz, bz) : dz);
                                cd = __fadd_rn(__fadd_rn(__fmul_rn(dx, dx), __fmul_rn(dy, dy)),
                                               __fmul_rn(dz, dz));
                                ci = j;
                            }
                        }
                        if (lex_less(cd, ci, d[K-1], id[K-1])) {
                            bool lt[K];
#pragma unroll
                            for (int m = 0; m < K; ++m) lt[m] = lex_less(cd, ci, d[m], id[m]);
#pragma unroll
                            for (int m = K-1; m >= 1; --m) {
                                d[m]  = lt[m-1] ? d[m-1]  : (lt[m] ? cd : d[m]);
                                id[m] = lt[m-1] ? id[m-1] : (lt[m] ? ci : id[m]);
                            }
                            d[0]  = lt[0] ? cd : d[0];
                            id[0] = lt[0] ? ci : id[0];
                        }
                    }
                }
            }

#pragma unroll 1
            for (int e = 0; e < K; ++e) {
                float bv = d[0]; int bi = id[0];
#pragma unroll
                for (int off = 32; off >= 1; off >>= 1) {
                    float ov = __shfl_xor(bv, off, WAVE);
                    int   oi = __shfl_xor(bi, off, WAVE);
                    if (lex_less(ov, oi, bv, bi)) { bv = ov; bi = oi; }
                }
                if (d[0] == bv && id[0] == bi) {
#pragma unroll
                    for (int m = 0; m < K-1; ++m) { d[m] = d[m+1]; id[m] = id[m+1]; }
                    d[K-1] = INFINITY; id[K-1] = 0x7fffffff;
                }
                if (lane == e) { md = bv; mi = bi; }
            }

            float d17 = __shfl(md, K - 1, WAVE);
            done = (r >= G/2) || (d17 < (r*cmin)*(r*cmin)*0.9998f);

            if (!done) {
#pragma unroll
                for (int m = 0; m < K; ++m) { d[m] = INFINITY; id[m] = 0x7fffffff; }
                if (lane < K) { d[0] = md; id[0] = mi; }
            }
        }

        const long kN = (long)N * K;
        if (lane < K) {
            out[(long)i*K + lane]        = (float)i;
            out[kN + (long)i*K + lane]   = (float)mi;
            out[2*kN + (long)i*K + lane] = __fsqrt_rn(md);
        }
    }
}

extern "C" void kernel_launch(void* const* d_in, const int* in_sizes, int n_in,
                              void* d_out, int out_size, void* d_ws, size_t ws_size,
                              hipStream_t stream) {
    const float* pos = (const float*)d_in[0];
    const float* box = (const float*)d_in[1];
    const int N = in_sizes[0] / 3;

    unsigned char* ws = (unsigned char*)d_ws;
    int*    cellStart = (int*)ws;                 // (CELLS+1) ints
    float4* sp4       = (float4*)(ws + 4096);     // N float4: cell-sorted (x,y,z,idx)

    prep_kernel<<<dim3(1), dim3(1024), 0, stream>>>(pos, box, cellStart, sp4, N);
    knn_main<<<dim3((N + 3) / 4), dim3(256), 0, stream>>>(pos, box, sp4, cellStart,
                                                          (float*)d_out, N);
}